// Round 1
// baseline (302.868 us; speedup 1.0000x reference)
//
#include <hip/hip_runtime.h>

// DeltaRule: T=8192 step scan over B=4096 independent sequences.
// Diagonal-affine recurrence -> chunked parallel scan:
//   P1: per (chunk, seq) compose affine map (A0,B0,A1,B1)
//   P2: serial scan over chunks (per seq) -> chunk-start states (p0,p1)
//   P3: replay each chunk from exact start state, emit preds
// obs_prev at a chunk boundary is simply x[t0-1] (no scan needed for it).

constexpr int T_LEN  = 8192;
constexpr int B_SEQ  = 4096;
constexpr int B4     = B_SEQ / 4;       // 1024 float4 groups of sequences
constexpr int CHUNK  = 64;
constexpr int NCHUNK = T_LEN / CHUNK;   // 128
constexpr int BLOCK  = 256;

__device__ __forceinline__ float clamp01(float v) {
    return fminf(fmaxf(v, 0.0f), 1.0f);
}

// ---------------- Phase 1: compose per-chunk affine maps ----------------
__global__ __launch_bounds__(BLOCK) void p1_compose(
    const float4* __restrict__ x4, const float* __restrict__ lr_ptr,
    float4* __restrict__ cA0, float4* __restrict__ cB0,
    float4* __restrict__ cA1, float4* __restrict__ cB1)
{
    const int i  = blockIdx.x * BLOCK + threadIdx.x;   // seq-group 0..B4-1
    const int c  = blockIdx.y;                         // chunk
    const int t0 = c * CHUNK;
    const float lr = clamp01(*lr_ptr);

    float obs[4];
    float A0[4] = {1.f,1.f,1.f,1.f}, Bc0[4] = {0.f,0.f,0.f,0.f};
    float A1[4] = {1.f,1.f,1.f,1.f}, Bc1[4] = {0.f,0.f,0.f,0.f};

    if (c == 0) {
        obs[0]=obs[1]=obs[2]=obs[3]=0.f;
    } else {
        float4 o = x4[(size_t)(t0 - 1) * B4 + i];
        obs[0]=o.x; obs[1]=o.y; obs[2]=o.z; obs[3]=o.w;
    }

    for (int t = t0; t < t0 + CHUNK; ++t) {
        float4 xv = x4[(size_t)t * B4 + i];
        float xt[4] = {xv.x, xv.y, xv.z, xv.w};
        #pragma unroll
        for (int k = 0; k < 4; ++k) {
            float g  = 1.0f - obs[k];
            float l0 = lr * g;
            float l1 = lr * obs[k];
            float a0 = 1.0f - l0;
            float a1 = 1.0f - l1;
            A0[k] *= a0;  Bc0[k] = fmaf(a0, Bc0[k], l0 * xt[k]);
            A1[k] *= a1;  Bc1[k] = fmaf(a1, Bc1[k], l1 * xt[k]);
            obs[k] = xt[k];
        }
    }

    const size_t idx = (size_t)c * B4 + i;
    cA0[idx] = make_float4(A0[0], A0[1], A0[2], A0[3]);
    cB0[idx] = make_float4(Bc0[0], Bc0[1], Bc0[2], Bc0[3]);
    cA1[idx] = make_float4(A1[0], A1[1], A1[2], A1[3]);
    cB1[idx] = make_float4(Bc1[0], Bc1[1], Bc1[2], Bc1[3]);
}

// ---------------- Phase 2: scan over chunks, store chunk-start states ----------------
__global__ __launch_bounds__(BLOCK) void p2_scan(
    const float4* __restrict__ cA0, const float4* __restrict__ cB0,
    const float4* __restrict__ cA1, const float4* __restrict__ cB1,
    float4* __restrict__ sP0, float4* __restrict__ sP1)
{
    const int i = blockIdx.x * BLOCK + threadIdx.x;    // 0..B4-1
    float p0[4] = {0.5f,0.5f,0.5f,0.5f};
    float p1[4] = {0.5f,0.5f,0.5f,0.5f};

    for (int c = 0; c < NCHUNK; ++c) {
        const size_t idx = (size_t)c * B4 + i;
        sP0[idx] = make_float4(p0[0], p0[1], p0[2], p0[3]);
        sP1[idx] = make_float4(p1[0], p1[1], p1[2], p1[3]);
        float4 a0 = cA0[idx], b0 = cB0[idx];
        float4 a1 = cA1[idx], b1 = cB1[idx];
        p0[0] = fmaf(a0.x, p0[0], b0.x);
        p0[1] = fmaf(a0.y, p0[1], b0.y);
        p0[2] = fmaf(a0.z, p0[2], b0.z);
        p0[3] = fmaf(a0.w, p0[3], b0.w);
        p1[0] = fmaf(a1.x, p1[0], b1.x);
        p1[1] = fmaf(a1.y, p1[1], b1.y);
        p1[2] = fmaf(a1.z, p1[2], b1.z);
        p1[3] = fmaf(a1.w, p1[3], b1.w);
    }
}

// ---------------- Phase 3: replay chunks, emit predictions ----------------
__global__ __launch_bounds__(BLOCK) void p3_emit(
    const float4* __restrict__ x4, const float* __restrict__ lr_ptr,
    const float4* __restrict__ sP0, const float4* __restrict__ sP1,
    float4* __restrict__ out4)
{
    const int i  = blockIdx.x * BLOCK + threadIdx.x;   // seq-group 0..B4-1
    const int c  = blockIdx.y;                         // chunk
    const int t0 = c * CHUNK;
    const float lr = clamp01(*lr_ptr);

    const size_t sidx = (size_t)c * B4 + i;
    float4 P0 = sP0[sidx], P1 = sP1[sidx];
    float p0[4] = {P0.x, P0.y, P0.z, P0.w};
    float p1[4] = {P1.x, P1.y, P1.z, P1.w};

    float obs[4];
    if (c == 0) {
        obs[0]=obs[1]=obs[2]=obs[3]=0.f;
    } else {
        float4 o = x4[(size_t)(t0 - 1) * B4 + i];
        obs[0]=o.x; obs[1]=o.y; obs[2]=o.z; obs[3]=o.w;
    }

    for (int t = t0; t < t0 + CHUNK; ++t) {
        float4 xv = x4[(size_t)t * B4 + i];
        float xt[4] = {xv.x, xv.y, xv.z, xv.w};
        float pr[4];
        #pragma unroll
        for (int k = 0; k < 4; ++k) {
            float g = 1.0f - obs[k];
            p0[k] = fmaf(lr * g,      xt[k] - p0[k], p0[k]);
            p1[k] = fmaf(lr * obs[k], xt[k] - p1[k], p1[k]);
            // pred = p0*(1-x) + p1*x
            pr[k] = fmaf(p1[k] - p0[k], xt[k], p0[k]);
            obs[k] = xt[k];
        }
        out4[(size_t)t * B4 + i] = make_float4(pr[0], pr[1], pr[2], pr[3]);
    }
}

extern "C" void kernel_launch(void* const* d_in, const int* in_sizes, int n_in,
                              void* d_out, int out_size, void* d_ws, size_t ws_size,
                              hipStream_t stream) {
    const float4* x4  = (const float4*)d_in[0];
    const float*  lr  = (const float*)d_in[1];
    float4*       out = (float4*)d_out;

    // Workspace layout: 6 arrays of NCHUNK*B4 float4 (2 MiB each, 12 MiB total)
    const size_t n = (size_t)NCHUNK * B4;
    float4* cA0 = (float4*)d_ws;
    float4* cB0 = cA0 + n;
    float4* cA1 = cB0 + n;
    float4* cB1 = cA1 + n;
    float4* sP0 = cB1 + n;
    float4* sP1 = sP0 + n;

    dim3 grid(B4 / BLOCK, NCHUNK);   // 4 x 128 = 512 blocks
    p1_compose<<<grid, BLOCK, 0, stream>>>(x4, lr, cA0, cB0, cA1, cB1);
    p2_scan<<<dim3(B4 / BLOCK), BLOCK, 0, stream>>>(cA0, cB0, cA1, cB1, sP0, sP1);
    p3_emit<<<grid, BLOCK, 0, stream>>>(x4, lr, sP0, sP1, out);
}

// Round 2
// 252.993 us; speedup vs baseline: 1.1971x; 1.1971x over previous
//
#include <hip/hip_runtime.h>

// DeltaRule: T=8192 scan over B=4096 independent sequences.
// Diagonal-affine recurrence -> chunked parallel scan, 3 dispatches:
//   P1: per (chunk, seq) compose affine map (A0,B0,A1,B1); bit-pack x (x is exactly 0/1)
//   P2: parallel Kogge-Stone scan over the 128 chunk-maps (one block per seq-group)
//   P3: replay each chunk from its exact start state using packed bits, emit preds
// obs_prev at a chunk boundary is x[t0-1] (read directly, tiny).
//
// R1 changes vs R0: P2 was a 4-block serial loop (latency-bound, ~70us hidden
// under the 80us poison fills); now 1024-block shuffle scan. P3 no longer
// re-reads x (128 MiB saved) -- replays from 4 MiB of packed bits.

constexpr int T_LEN  = 8192;
constexpr int B_SEQ  = 4096;
constexpr int B4     = B_SEQ / 4;       // 1024 float4 seq-groups
constexpr int CHUNK  = 64;
constexpr int NCHUNK = T_LEN / CHUNK;   // 128
constexpr int BLOCK  = 256;

__device__ __forceinline__ float clamp01(float v) {
    return fminf(fmaxf(v, 0.0f), 1.0f);
}

// ---------------- Phase 1: compose per-chunk affine maps + pack bits ----------------
__global__ __launch_bounds__(BLOCK) void p1_compose(
    const float4* __restrict__ x4, const float* __restrict__ lr_ptr,
    float4* __restrict__ cA0, float4* __restrict__ cB0,
    float4* __restrict__ cA1, float4* __restrict__ cB1,
    uint4* __restrict__ bitsA, uint4* __restrict__ bitsB)
{
    const int i  = blockIdx.x * BLOCK + threadIdx.x;   // seq-group
    const int c  = blockIdx.y;                         // chunk
    const int t0 = c * CHUNK;
    const float lr = clamp01(*lr_ptr);

    float obs[4];
    if (c == 0) {
        obs[0]=obs[1]=obs[2]=obs[3]=0.f;
    } else {
        float4 o = x4[(size_t)(t0 - 1) * B4 + i];
        obs[0]=o.x; obs[1]=o.y; obs[2]=o.z; obs[3]=o.w;
    }

    float A0[4]  = {1.f,1.f,1.f,1.f}, Bc0[4] = {0.f,0.f,0.f,0.f};
    float A1[4]  = {1.f,1.f,1.f,1.f}, Bc1[4] = {0.f,0.f,0.f,0.f};
    unsigned long long bits[4] = {0ull,0ull,0ull,0ull};

    #pragma unroll 8
    for (int t = 0; t < CHUNK; ++t) {
        float4 xv = x4[(size_t)(t0 + t) * B4 + i];
        float xt[4] = {xv.x, xv.y, xv.z, xv.w};
        #pragma unroll
        for (int k = 0; k < 4; ++k) {
            bits[k] |= ((unsigned long long)(xt[k] != 0.0f)) << t;
            float g  = 1.0f - obs[k];          // exact: obs in {0,1}
            float l0 = lr * g;                 // obs=0 -> lr ; obs=1 -> 0
            float l1 = lr - l0;                // exact complement
            float a0 = 1.0f - l0;
            float a1 = 1.0f - l1;
            Bc0[k] = fmaf(a0, Bc0[k], l0 * xt[k]);  A0[k] *= a0;
            Bc1[k] = fmaf(a1, Bc1[k], l1 * xt[k]);  A1[k] *= a1;
            obs[k] = xt[k];
        }
    }

    const size_t idx = (size_t)c * B4 + i;
    cA0[idx] = make_float4(A0[0], A0[1], A0[2], A0[3]);
    cB0[idx] = make_float4(Bc0[0], Bc0[1], Bc0[2], Bc0[3]);
    cA1[idx] = make_float4(A1[0], A1[1], A1[2], A1[3]);
    cB1[idx] = make_float4(Bc1[0], Bc1[1], Bc1[2], Bc1[3]);
    bitsA[idx] = make_uint4((unsigned)bits[0], (unsigned)(bits[0] >> 32),
                            (unsigned)bits[1], (unsigned)(bits[1] >> 32));
    bitsB[idx] = make_uint4((unsigned)bits[2], (unsigned)(bits[2] >> 32),
                            (unsigned)bits[3], (unsigned)(bits[3] >> 32));
}

// ---------------- Phase 2: parallel scan over chunks ----------------
// One block (128 threads = 2 waves) per seq-group; thread c holds chunk c's map.
// Intra-wave Kogge-Stone via shuffles, cross-wave combine + exclusive shift via LDS.

__device__ __forceinline__ float4 shfl_up4(float4 v, int d) {
    float4 r;
    r.x = __shfl_up(v.x, d);
    r.y = __shfl_up(v.y, d);
    r.z = __shfl_up(v.z, d);
    r.w = __shfl_up(v.w, d);
    return r;
}

// m := m ∘ p (p applied first):  B = fma(A_self, B_pred, B_self); A = A_self*A_pred
#define COMPOSE4(Aa, Bb, pA, pB)                         \
    Bb.x = fmaf(Aa.x, pB.x, Bb.x);  Aa.x *= pA.x;        \
    Bb.y = fmaf(Aa.y, pB.y, Bb.y);  Aa.y *= pA.y;        \
    Bb.z = fmaf(Aa.z, pB.z, Bb.z);  Aa.z *= pA.z;        \
    Bb.w = fmaf(Aa.w, pB.w, Bb.w);  Aa.w *= pA.w;

__global__ __launch_bounds__(NCHUNK) void p2_scan(
    const float4* __restrict__ cA0, const float4* __restrict__ cB0,
    const float4* __restrict__ cA1, const float4* __restrict__ cB1,
    float4* __restrict__ sP0, float4* __restrict__ sP1)
{
    const int i    = blockIdx.x;        // seq-group
    const int c    = threadIdx.x;       // chunk 0..127
    const int lane = c & 63;

    const size_t idx = (size_t)c * B4 + i;
    float4 A0 = cA0[idx], B0 = cB0[idx];
    float4 A1 = cA1[idx], B1 = cB1[idx];

    // intra-wave inclusive scan
    #pragma unroll
    for (int d = 1; d < 64; d <<= 1) {
        float4 pA0 = shfl_up4(A0, d), pB0 = shfl_up4(B0, d);
        float4 pA1 = shfl_up4(A1, d), pB1 = shfl_up4(B1, d);
        if (lane >= d) {
            COMPOSE4(A0, B0, pA0, pB0);
            COMPOSE4(A1, B1, pA1, pB1);
        }
    }

    __shared__ float4 tA0, tB0, tA1, tB1;              // wave-0 total
    __shared__ float4 sA0[NCHUNK], sB0[NCHUNK], sA1[NCHUNK], sB1[NCHUNK];

    if (c == 63) { tA0 = A0; tB0 = B0; tA1 = A1; tB1 = B1; }
    __syncthreads();
    if (c >= 64) {           // prepend wave-0 total
        COMPOSE4(A0, B0, tA0, tB0);
        COMPOSE4(A1, B1, tA1, tB1);
    }
    sA0[c] = A0; sB0[c] = B0; sA1[c] = A1; sB1[c] = B1;
    __syncthreads();

    float4 eA0, eB0, eA1, eB1;         // exclusive = inclusive of c-1
    if (c == 0) {
        eA0 = make_float4(1,1,1,1); eB0 = make_float4(0,0,0,0);
        eA1 = make_float4(1,1,1,1); eB1 = make_float4(0,0,0,0);
    } else {
        eA0 = sA0[c-1]; eB0 = sB0[c-1];
        eA1 = sA1[c-1]; eB1 = sB1[c-1];
    }
    // chunk-start state = A*0.5 + B
    sP0[idx] = make_float4(fmaf(eA0.x, 0.5f, eB0.x), fmaf(eA0.y, 0.5f, eB0.y),
                           fmaf(eA0.z, 0.5f, eB0.z), fmaf(eA0.w, 0.5f, eB0.w));
    sP1[idx] = make_float4(fmaf(eA1.x, 0.5f, eB1.x), fmaf(eA1.y, 0.5f, eB1.y),
                           fmaf(eA1.z, 0.5f, eB1.z), fmaf(eA1.w, 0.5f, eB1.w));
}

// ---------------- Phase 3: replay from packed bits, emit predictions ----------------
__global__ __launch_bounds__(BLOCK) void p3_emit(
    const float4* __restrict__ x4, const float* __restrict__ lr_ptr,
    const float4* __restrict__ sP0, const float4* __restrict__ sP1,
    const uint4* __restrict__ bitsA, const uint4* __restrict__ bitsB,
    float4* __restrict__ out4)
{
    const int i  = blockIdx.x * BLOCK + threadIdx.x;   // seq-group
    const int c  = blockIdx.y;                         // chunk
    const int t0 = c * CHUNK;
    const float lr = clamp01(*lr_ptr);

    const size_t idx = (size_t)c * B4 + i;
    float4 P0 = sP0[idx], P1 = sP1[idx];
    float p0[4] = {P0.x, P0.y, P0.z, P0.w};
    float p1[4] = {P1.x, P1.y, P1.z, P1.w};

    uint4 ba = bitsA[idx], bb = bitsB[idx];
    unsigned lo[4] = {ba.x, ba.z, bb.x, bb.z};
    unsigned hi[4] = {ba.y, ba.w, bb.y, bb.w};

    float obs[4];
    if (c == 0) {
        obs[0]=obs[1]=obs[2]=obs[3]=0.f;
    } else {
        float4 o = x4[(size_t)(t0 - 1) * B4 + i];
        obs[0]=o.x; obs[1]=o.y; obs[2]=o.z; obs[3]=o.w;
    }

    #pragma unroll 8
    for (int t = 0; t < CHUNK; ++t) {
        float pr[4];
        #pragma unroll
        for (int k = 0; k < 4; ++k) {
            unsigned w   = (t < 32) ? lo[k] : hi[k];
            unsigned bit = (w >> (t & 31)) & 1u;
            float xf = (float)bit;                 // exact 0.0 / 1.0
            float g  = 1.0f - obs[k];
            float l0 = lr * g;
            float l1 = lr - l0;
            p0[k] = fmaf(l0, xf - p0[k], p0[k]);
            p1[k] = fmaf(l1, xf - p1[k], p1[k]);
            pr[k] = bit ? p1[k] : p0[k];           // exact select, matches ref
            obs[k] = xf;
        }
        out4[(size_t)(t0 + t) * B4 + i] = make_float4(pr[0], pr[1], pr[2], pr[3]);
    }
}

extern "C" void kernel_launch(void* const* d_in, const int* in_sizes, int n_in,
                              void* d_out, int out_size, void* d_ws, size_t ws_size,
                              hipStream_t stream) {
    const float4* x4  = (const float4*)d_in[0];
    const float*  lr  = (const float*)d_in[1];
    float4*       out = (float4*)d_out;

    // Workspace: 6 float4 arrays + 2 uint4 arrays, each NCHUNK*B4 elems (2 MiB) = 16 MiB
    const size_t n = (size_t)NCHUNK * B4;
    float4* cA0 = (float4*)d_ws;
    float4* cB0 = cA0 + n;
    float4* cA1 = cB0 + n;
    float4* cB1 = cA1 + n;
    float4* sP0 = cB1 + n;
    float4* sP1 = sP0 + n;
    uint4*  bitsA = (uint4*)(sP1 + n);
    uint4*  bitsB = bitsA + n;

    dim3 grid13(B4 / BLOCK, NCHUNK);   // 4 x 128 = 512 blocks
    p1_compose<<<grid13, BLOCK, 0, stream>>>(x4, lr, cA0, cB0, cA1, cB1, bitsA, bitsB);
    p2_scan<<<dim3(B4), NCHUNK, 0, stream>>>(cA0, cB0, cA1, cB1, sP0, sP1);
    p3_emit<<<grid13, BLOCK, 0, stream>>>(x4, lr, sP0, sP1, bitsA, bitsB, out);
}